// Round 11
// baseline (74.922 us; speedup 1.0000x reference)
//
#include <hip/hip_runtime.h>

// Problem constants: V=128, E=256, H=4, B=1024, L=64
// Algebra: attn out folds V away: out = sv @ Wv^T, Wv folded into fc (W').
//          QK^T = Y @ x2^T with Y = X2 @ (Wq^T Wk) (NT precomputed, per head).
// 4 launches: prep (x2t+NT+wfold+posmean) -> gemm128 (Y, XCD-swizzled)
//   -> attn (sv + xmean) -> fcfin (fc GEMM + 4-LN chain).

typedef __attribute__((ext_vector_type(8))) short bf16x8;
typedef __attribute__((ext_vector_type(4))) float f32x4;

__device__ __forceinline__ float wred_sum(float v) {
#pragma unroll
  for (int off = 32; off > 0; off >>= 1) v += __shfl_xor(v, off, 64);
  return v;
}
__device__ __forceinline__ float bf2f(unsigned short u) {
  union { unsigned int i; float f; } x; x.i = ((unsigned int)u) << 16; return x.f;
}
__device__ __forceinline__ unsigned short f2bf(float f) {
  union { float f; unsigned int i; } x; x.f = f;
  unsigned int r = x.i + 0x7FFFu + ((x.i >> 16) & 1u);
  return (unsigned short)(r >> 16);
}
__device__ __forceinline__ void gld16(const unsigned short* g, unsigned short* l) {
  __builtin_amdgcn_global_load_lds(
      (const __attribute__((address_space(1))) unsigned int*)g,
      (__attribute__((address_space(3))) unsigned int*)l, 16, 0, 0);
}
// fast freq = 10000^(-i/128) = exp2(-i * log2(1e4)/128)
__device__ __forceinline__ float fast_freq(float i) {
  return exp2f(i * (-13.287712379549449f / 128.0f));
}

// ---------------- prep super-kernel ----------------
// blocks 0..63:    NT[h] tiles:    NT[h][e2][e1] = sum_i Wk[i,e2] Wq[i,e1]
// blocks 64..127:  wfold tiles:    wfold[o][h*256+e] = sum_e' fc_w[o][h*256+e'] Wv_h[e'][e]
// block 128:       posmean
// blocks 129..2176: x2t rows (4/block)
__global__ __launch_bounds__(256) void prep_kernel(const float* qkv_w, const float* fc_w,
                                                   const float* emb, const float* ln0_g,
                                                   const float* ln0_b, float* posmean,
                                                   unsigned short* NTb, unsigned short* wfoldb,
                                                   unsigned short* x2tb) {
  __shared__ float T[64][65];
  __shared__ unsigned short As[64 * 64];
  __shared__ unsigned short Bs[64 * 64];
  int bid = blockIdx.x, t = threadIdx.x;

  if (bid < 128) {
    int w = t >> 6, lane = t & 63;
    int li = lane & 15, hi = lane >> 4;
    int r = t >> 4, c4 = (t & 15) * 4;
    bool isNT = bid < 64;
    int sub = isNT ? bid : bid - 64;
    int h = sub >> 4;
    int tm = (sub >> 2) & 3;
    int tn = sub & 3;
    int m0 = tm * 64, n0 = tn * 64;
    f32x4 acc[4] = {};
    for (int kt = 0; kt < 4; ++kt) {
      int k0 = kt * 64;
      if (isNT) {
        __syncthreads();
#pragma unroll
        for (int rep = 0; rep < 4; ++rep) {
          int il = rep * 16 + r;
          float4 v = *(const float4*)(qkv_w + (size_t)(h * 768 + 256 + k0 + il) * 256 + m0 + c4);
          T[il][c4] = v.x; T[il][c4 + 1] = v.y; T[il][c4 + 2] = v.z; T[il][c4 + 3] = v.w;
        }
        __syncthreads();
#pragma unroll
        for (int rep = 0; rep < 4; ++rep) {
          int el = rep * 16 + r;
          As[el * 64 + c4 + 0] = f2bf(T[c4 + 0][el]);
          As[el * 64 + c4 + 1] = f2bf(T[c4 + 1][el]);
          As[el * 64 + c4 + 2] = f2bf(T[c4 + 2][el]);
          As[el * 64 + c4 + 3] = f2bf(T[c4 + 3][el]);
        }
      } else {
        __syncthreads();
#pragma unroll
        for (int rep = 0; rep < 4; ++rep) {
          int rl = rep * 16 + r;
          float4 v = *(const float4*)(fc_w + (size_t)(m0 + rl) * 1024 + h * 256 + k0 + c4);
          As[rl * 64 + c4 + 0] = f2bf(v.x);
          As[rl * 64 + c4 + 1] = f2bf(v.y);
          As[rl * 64 + c4 + 2] = f2bf(v.z);
          As[rl * 64 + c4 + 3] = f2bf(v.w);
        }
      }
      {
        int sel = isNT ? 0 : 512;
        __syncthreads();
#pragma unroll
        for (int rep = 0; rep < 4; ++rep) {
          int il = rep * 16 + r;
          float4 v = *(const float4*)(qkv_w + (size_t)(h * 768 + sel + k0 + il) * 256 + n0 + c4);
          T[il][c4] = v.x; T[il][c4 + 1] = v.y; T[il][c4 + 2] = v.z; T[il][c4 + 3] = v.w;
        }
        __syncthreads();
#pragma unroll
        for (int rep = 0; rep < 4; ++rep) {
          int el = rep * 16 + r;
          Bs[el * 64 + c4 + 0] = f2bf(T[c4 + 0][el]);
          Bs[el * 64 + c4 + 1] = f2bf(T[c4 + 1][el]);
          Bs[el * 64 + c4 + 2] = f2bf(T[c4 + 2][el]);
          Bs[el * 64 + c4 + 3] = f2bf(T[c4 + 3][el]);
        }
      }
      __syncthreads();
#pragma unroll
      for (int kk = 0; kk < 2; ++kk) {
        bf16x8 bf = *(const bf16x8*)(Bs + (w * 16 + li) * 64 + kk * 32 + hi * 8);
#pragma unroll
        for (int m = 0; m < 4; ++m) {
          bf16x8 af = *(const bf16x8*)(As + (m * 16 + li) * 64 + kk * 32 + hi * 8);
          acc[m] = __builtin_amdgcn_mfma_f32_16x16x32_bf16(af, bf, acc[m], 0, 0, 0);
        }
      }
    }
    if (isNT) {
      unsigned short* C = NTb + (size_t)h * 65536;
      int col = n0 + w * 16 + li;
#pragma unroll
      for (int m = 0; m < 4; ++m)
#pragma unroll
        for (int j = 0; j < 4; ++j)
          C[(size_t)(m0 + m * 16 + hi * 4 + j) * 256 + col] = f2bf(acc[m][j]);
    } else {
      int col = h * 256 + n0 + w * 16 + li;
#pragma unroll
      for (int m = 0; m < 4; ++m)
#pragma unroll
        for (int j = 0; j < 4; ++j)
          wfoldb[(size_t)(m0 + m * 16 + hi * 4 + j) * 1024 + col] = f2bf(acc[m][j]);
    }
  } else if (bid == 128) {
    int e = t;
    float freq = fast_freq((float)(e >> 1));
    float s = 0.f;
    for (int l = 0; l < 64; ++l) {
      float ph = (float)l * freq;
      s += (e & 1) ? __cosf(ph) : __sinf(ph);
    }
    posmean[e] = s * (1.0f / 64.0f);
  } else {
    int w = t >> 6, lane = t & 63;
    int row = (bid - 129) * 4 + w;
    int c = row >> 6, l = row & 63;
    int e0 = lane * 4;
    float fr0 = fast_freq((float)(e0 >> 1));
    float fr1 = fast_freq((float)(e0 >> 1) + 1.0f);
    float p0 = (float)l * fr0, p1 = (float)l * fr1;
    float4 pv = make_float4(__sinf(p0), __cosf(p0), __sinf(p1), __cosf(p1));
    float4 ev = *(const float4*)(emb + c * 256 + e0);
    float v0 = ev.x + pv.x, v1 = ev.y + pv.y, v2 = ev.z + pv.z, v3 = ev.w + pv.w;
    float s = wred_sum(v0 + v1 + v2 + v3);
    float q = wred_sum(v0 * v0 + v1 * v1 + v2 * v2 + v3 * v3);
    float mean = s * (1.0f / 256.0f);
    float var = q * (1.0f / 256.0f) - mean * mean;
    float rstd = rsqrtf(var + 1e-5f);
    float4 gv = *(const float4*)(ln0_g + e0);
    float4 bv = *(const float4*)(ln0_b + e0);
    *(ushort4*)(x2tb + (size_t)row * 256 + e0) = make_ushort4(
        f2bf((v0 - mean) * rstd * gv.x + bv.x + pv.x),
        f2bf((v1 - mean) * rstd * gv.y + bv.y + pv.y),
        f2bf((v2 - mean) * rstd * gv.z + bv.z + pv.z),
        f2bf((v3 - mean) * rstd * gv.w + bv.w + pv.w));
  }
}

// ---------------- Y GEMM (flattened grid 512, XCD-swizzled) ----------------
// yt[r][h*256+e2] = sum_e1 x2tb[r][e1] * NT[h][e2][e1]
__global__ __launch_bounds__(256) void gemm128_kernel(const unsigned short* A,
                                                      const unsigned short* B,
                                                      unsigned short* C) {
  __shared__ unsigned short S[2 * 128 * 64];
  unsigned short* As = S;
  unsigned short* Bs = S + 128 * 64;
  int t = threadIdx.x, w = t >> 6, lane = t & 63;
  // bijective XCD swizzle (512 % 8 == 0): same-z blocks share an XCD's L2
  int bid = blockIdx.x;
  int swz = (bid & 7) * 64 + (bid >> 3);
  int xb = swz & 1, yb = (swz >> 1) & 63, z = swz >> 7;
  int m0 = yb * 128, n0 = xb * 128;
  B += (size_t)z * 65536;
  int wr = w >> 1, wc = w & 1;
  f32x4 acc[4][4] = {};
  int r_in = lane >> 3, cb = (lane & 7) * 8;
  for (int kt = 0; kt < 4; ++kt) {
#pragma unroll
    for (int it = 0; it < 4; ++it) {
      int rowblk = it * 32 + w * 8;
      gld16(A + (size_t)(m0 + rowblk + r_in) * 256 + kt * 64 + cb, As + rowblk * 64);
      gld16(B + (size_t)(n0 + rowblk + r_in) * 256 + kt * 64 + cb, Bs + rowblk * 64);
    }
    __syncthreads();
#pragma unroll
    for (int kk = 0; kk < 2; ++kk) {
      bf16x8 af[4], bfr[4];
#pragma unroll
      for (int m = 0; m < 4; ++m)
        af[m] = *(const bf16x8*)(As + (wr * 64 + m * 16 + (lane & 15)) * 64 + kk * 32 + (lane >> 4) * 8);
#pragma unroll
      for (int n = 0; n < 4; ++n)
        bfr[n] = *(const bf16x8*)(Bs + (wc * 64 + n * 16 + (lane & 15)) * 64 + kk * 32 + (lane >> 4) * 8);
#pragma unroll
      for (int m = 0; m < 4; ++m)
#pragma unroll
        for (int n = 0; n < 4; ++n)
          acc[m][n] = __builtin_amdgcn_mfma_f32_16x16x32_bf16(af[m], bfr[n], acc[m][n], 0, 0, 0);
    }
    __syncthreads();
  }
  unsigned short* Cs = S;
#pragma unroll
  for (int m = 0; m < 4; ++m)
#pragma unroll
    for (int n = 0; n < 4; ++n) {
      int row = wr * 64 + m * 16 + ((lane >> 4)) * 4;
      int col = wc * 64 + n * 16 + (lane & 15);
#pragma unroll
      for (int j = 0; j < 4; ++j)
        Cs[(row + j) * 128 + col] = f2bf(acc[m][n][j]);
    }
  __syncthreads();
#pragma unroll
  for (int it = 0; it < 8; ++it) {
    int row = it * 16 + (t >> 4);
    int ce = (t & 15) * 8;
    *(bf16x8*)(C + (size_t)(m0 + row) * 1024 + z * 256 + n0 + ce) =
        *(const bf16x8*)(Cs + row * 128 + ce);
  }
}

// ---------------- attention: block = b (512 thr, 8 waves); wave = (head, q-half) ----------------
// No-max softmax (exp args bounded); emits sv + xmean.
__global__ __launch_bounds__(512, 4) void attn_kernel(const int* cc, const unsigned short* yt,
                                                      const unsigned short* x2tb,
                                                      const float* posmean,
                                                      unsigned short* svb, float* xmb) {
  __shared__ unsigned short X2s[4 * 4112];
  __shared__ float s_sp[8][64];
  __shared__ float s_nm[64];
  __shared__ int s_cc[64];
  __shared__ float s_nwinv;
  int b = blockIdx.x;
  int t = threadIdx.x, w = t >> 6, lane = t & 63;
  int li = lane & 15, hi = lane >> 4;
  int h = w >> 1, mh = w & 1;

  if (t < 64) {
    int c = cc[b * 64 + t];
    s_cc[t] = c;
    s_nm[t] = (c != 0) ? 1.0f : 0.0f;
  }
  __syncthreads();
  if (t < 64) {
    float s = wred_sum(s_nm[t]);
    if (t == 0) s_nwinv = 1.0f / s;
  }

  int sr = lane >> 3;
  int sg = (lane & 7) ^ sr;
  {
    int idx = w * 8 + sr;
    size_t rbase = (size_t)(s_cc[idx] * 64 + idx) * 256;
#pragma unroll
    for (int ecc = 0; ecc < 4; ++ecc)
      gld16(x2tb + rbase + ecc * 64 + sg * 8, X2s + ecc * 4112 + w * 512);
  }

  const unsigned short* rowp[2];
#pragma unroll
  for (int m = 0; m < 2; ++m) {
    int idx = mh * 32 + m * 16 + li;
    rowp[m] = yt + (size_t)(s_cc[idx] * 64 + idx) * 1024 + h * 256;
  }
  float nmv[4];
#pragma unroll
  for (int n = 0; n < 4; ++n) nmv[n] = s_nm[n * 16 + li];

  bf16x8 ybuf[4][4];
#pragma unroll
  for (int ec = 0; ec < 2; ++ec)
#pragma unroll
    for (int kk = 0; kk < 2; ++kk)
#pragma unroll
      for (int m = 0; m < 2; ++m)
        ybuf[ec][kk * 2 + m] = *(const bf16x8*)(rowp[m] + ec * 64 + kk * 32 + hi * 8);

  __syncthreads();

  f32x4 acc[2][4] = {};
#pragma unroll
  for (int ec = 0; ec < 4; ++ec) {
    if (ec < 2) {
#pragma unroll
      for (int kk = 0; kk < 2; ++kk)
#pragma unroll
        for (int m = 0; m < 2; ++m)
          ybuf[ec + 2][kk * 2 + m] = *(const bf16x8*)(rowp[m] + (ec + 2) * 64 + kk * 32 + hi * 8);
    }
    __builtin_amdgcn_sched_barrier(0);
    __builtin_amdgcn_s_setprio(1);
#pragma unroll
    for (int kk = 0; kk < 2; ++kk)
#pragma unroll
      for (int n = 0; n < 4; ++n) {
        int rk = n * 16 + li;
        bf16x8 bf = *(const bf16x8*)(X2s + ec * 4112 + rk * 64 + (((kk * 4 + hi) ^ (rk & 7)) * 8));
#pragma unroll
        for (int m = 0; m < 2; ++m)
          acc[m][n] = __builtin_amdgcn_mfma_f32_16x16x32_bf16(ybuf[ec][kk * 2 + m], bf, acc[m][n], 0, 0, 0);
      }
    __builtin_amdgcn_s_setprio(0);
  }

  float sc[4] = {0.f, 0.f, 0.f, 0.f};
#pragma unroll
  for (int m = 0; m < 2; ++m)
#pragma unroll
    for (int j = 0; j < 4; ++j) {
      float nmq = s_nm[mh * 32 + m * 16 + hi * 4 + j];
      float p[4];
#pragma unroll
      for (int n = 0; n < 4; ++n) p[n] = nmv[n] * __expf(acc[m][n][j] * 0.0625f);
      float s = (p[0] + p[1]) + (p[2] + p[3]);
      s += __shfl_xor(s, 1, 64);
      s += __shfl_xor(s, 2, 64);
      s += __shfl_xor(s, 4, 64);
      s += __shfl_xor(s, 8, 64);
      float f = nmq / s;
#pragma unroll
      for (int n = 0; n < 4; ++n) sc[n] += p[n] * f;
    }
#pragma unroll
  for (int n = 0; n < 4; ++n) {
    sc[n] += __shfl_xor(sc[n], 16, 64);
    sc[n] += __shfl_xor(sc[n], 32, 64);
  }
  if (hi == 0) {
#pragma unroll
    for (int n = 0; n < 4; ++n) s_sp[w][n * 16 + li] = sc[n];
  }
  __syncthreads();

  {
    float nwinv = s_nwinv;
    int c0 = mh * 128 + lane * 2;
    int chunk = c0 >> 6;
    int cin = c0 & 63;
    int cg = cin >> 3, ce = cin & 7;
    const unsigned short* Xc = X2s + chunk * 4112;
    const float* spa = s_sp[h * 2];
    const float* spb = s_sp[h * 2 + 1];
    float o0 = 0.f, o1 = 0.f;
#pragma unroll
    for (int k = 0; k < 64; ++k) {
      float sk = (spa[k] + spb[k]) * nwinv;
      const unsigned short* p = Xc + k * 64 + ((cg ^ (k & 7)) * 8) + ce;
      o0 = fmaf(sk, bf2f(p[0]), o0);
      o1 = fmaf(sk, bf2f(p[1]), o1);
    }
    ushort2 ov; ov.x = f2bf(o0); ov.y = f2bf(o1);
    *(ushort2*)(svb + (size_t)b * 1024 + h * 256 + c0) = ov;
  }

  {
    int cidx = w * 32 + (lane & 31);
    int chunk = cidx >> 6, cin = cidx & 63;
    int cg = cin >> 3, ce = cin & 7;
    const unsigned short* Xc = X2s + chunk * 4112;
    int r0 = lane >> 5;
    float s = 0.f;
#pragma unroll
    for (int kk = 0; kk < 32; ++kk) {
      int k = r0 + kk * 2;
      s += bf2f(Xc[k * 64 + ((cg ^ (k & 7)) * 8) + ce]);
    }
    s += __shfl_xor(s, 32, 64);
    if (lane < 32)
      xmb[(size_t)b * 256 + cidx] = s * (1.0f / 64.0f) - posmean[cidx];
  }
}

// ---------------- fcfin: fc GEMM (16 batches/block, K=1024) + 4-LN chain ----------------
__device__ __forceinline__ float4 ln4(float4 v, const float* g, const float* b, int e0,
                                      float eps) {
  float s = wred_sum(v.x + v.y + v.z + v.w);
  float q = wred_sum(v.x * v.x + v.y * v.y + v.z * v.z + v.w * v.w);
  float mean = s * (1.0f / 256.0f);
  float var = q * (1.0f / 256.0f) - mean * mean;
  float rstd = rsqrtf(var + eps);
  float4 g4 = *(const float4*)(g + e0);
  float4 b4 = *(const float4*)(b + e0);
  return make_float4((v.x - mean) * rstd * g4.x + b4.x,
                     (v.y - mean) * rstd * g4.y + b4.y,
                     (v.z - mean) * rstd * g4.z + b4.z,
                     (v.w - mean) * rstd * g4.w + b4.w);
}

__global__ __launch_bounds__(512) void fcfin_kernel(
    const unsigned short* svbp, const unsigned short* wfoldb, const float* fc_b,
    const float* xmb,
    const float* sln_g, const float* sln_b, const float* ln1_g, const float* ln1_b,
    const float* ffln_g, const float* ffln_b, const float* ln2_g, const float* ln2_b,
    float* out) {
  __shared__ unsigned short As[16 * 64];    // 2KB: 16 batch rows x 64 k
  __shared__ unsigned short Bs[256 * 64];   // 32KB: 256 o-rows x 64 k
  __shared__ float Outs[16 * 256];          // 16KB
  int t = threadIdx.x, w = t >> 6, lane = t & 63;
  int li = lane & 15, hi = lane >> 4;
  int m0 = blockIdx.x * 16;                 // 16 batches
  int sr = lane >> 3, sg = lane & 7;
  f32x4 acc[2] = {};
  for (int kt = 0; kt < 16; ++kt) {
    if (w < 2) {                            // As: 16 rows (2 waves x 8 rows)
      int row = w * 8 + sr;
      gld16(svbp + (size_t)(m0 + row) * 1024 + kt * 64 + sg * 8, As + w * 512);
    }
#pragma unroll
    for (int it = 0; it < 4; ++it) {        // Bs: 256 rows (8 waves x 4 x 8 rows)
      int rowblk = it * 64 + w * 8;
      gld16(wfoldb + (size_t)(rowblk + sr) * 1024 + kt * 64 + sg * 8, Bs + rowblk * 64);
    }
    __syncthreads();
#pragma unroll
    for (int kk = 0; kk < 2; ++kk) {
      bf16x8 af = *(const bf16x8*)(As + li * 64 + kk * 32 + hi * 8);
#pragma unroll
      for (int nn = 0; nn < 2; ++nn) {
        bf16x8 bf = *(const bf16x8*)(Bs + (w * 32 + nn * 16 + li) * 64 + kk * 32 + hi * 8);
        acc[nn] = __builtin_amdgcn_mfma_f32_16x16x32_bf16(af, bf, acc[nn], 0, 0, 0);
      }
    }
    __syncthreads();
  }
  // acc[nn][j]: batch-row = hi*4+j, col = w*32 + nn*16 + li
#pragma unroll
  for (int nn = 0; nn < 2; ++nn)
#pragma unroll
    for (int j = 0; j < 4; ++j)
      Outs[(hi * 4 + j) * 256 + w * 32 + nn * 16 + li] = acc[nn][j];
  __syncthreads();

  // LN chain: wave w handles batches w*2, w*2+1; lane owns cols lane*4..+3
  int e0 = lane * 4;
  float4 bias = *(const float4*)(fc_b + e0);
#pragma unroll
  for (int bb = 0; bb < 2; ++bb) {
    int row = w * 2 + bb;
    int gb = m0 + row;
    float4 v = *(const float4*)(Outs + row * 256 + e0);
    v.x += bias.x; v.y += bias.y; v.z += bias.z; v.w += bias.w;
    v = ln4(v, sln_g, sln_b, e0, 1e-5f);
    float4 xm = *(const float4*)(xmb + (size_t)gb * 256 + e0);
    v.x += xm.x; v.y += xm.y; v.z += xm.z; v.w += xm.w;
    v = ln4(v, ln1_g, ln1_b, e0, 1e-5f);
    float4 ff = ln4(v, ffln_g, ffln_b, e0, 1e-6f);
    float4 w2 = make_float4(v.x + ff.x, v.y + ff.y, v.z + ff.z, v.w + ff.w);
    float4 fin = ln4(w2, ln2_g, ln2_b, e0, 1e-5f);
    *(float4*)(out + (size_t)gb * 256 + e0) = fin;
  }
}

extern "C" void kernel_launch(void* const* d_in, const int* in_sizes, int n_in,
                              void* d_out, int out_size, void* d_ws, size_t ws_size,
                              hipStream_t stream) {
  const int* char_code = (const int*)d_in[0];
  const float* emb    = (const float*)d_in[2];
  const float* qkv_w  = (const float*)d_in[3];
  const float* ln0_g  = (const float*)d_in[4];
  const float* ln0_b  = (const float*)d_in[5];
  const float* fc_w   = (const float*)d_in[6];
  const float* fc_b   = (const float*)d_in[7];
  const float* sln_g  = (const float*)d_in[8];
  const float* sln_b  = (const float*)d_in[9];
  const float* ln1_g  = (const float*)d_in[10];
  const float* ln1_b  = (const float*)d_in[11];
  const float* ffln_g = (const float*)d_in[16];
  const float* ffln_b = (const float*)d_in[17];
  const float* ln2_g  = (const float*)d_in[18];
  const float* ln2_b  = (const float*)d_in[19];

  float* ws = (float*)d_ws;
  float* posmean = ws;                                      // 256 f32
  unsigned short* x2tb  = (unsigned short*)(posmean + 256); // 8192*256
  unsigned short* yt    = x2tb + (size_t)8192 * 256;        // 8192*1024
  unsigned short* NTb   = yt + (size_t)8192 * 1024;         // 4*256*256
  unsigned short* wfoldb= NTb + 262144;                     // 256*1024
  unsigned short* svb   = wfoldb + 262144;                  // 1024*1024
  float* xmb = (float*)(svb + (size_t)1024 * 1024);         // 1024*256 f32

  prep_kernel<<<2177, 256, 0, stream>>>(qkv_w, fc_w, emb, ln0_g, ln0_b, posmean,
                                        NTb, wfoldb, x2tb);
  gemm128_kernel<<<512, 256, 0, stream>>>(x2tb, NTb, yt);
  attn_kernel<<<1024, 512, 0, stream>>>(char_code, yt, x2tb, posmean, svb, xmb);
  fcfin_kernel<<<64, 512, 0, stream>>>(svb, wfoldb, fc_b, xmb,
                                       sln_g, sln_b, ln1_g, ln1_b,
                                       ffln_g, ffln_b, ln2_g, ln2_b, (float*)d_out);
}

// Round 12
// 65.593 us; speedup vs baseline: 1.1422x; 1.1422x over previous
//
#include <hip/hip_runtime.h>

// Problem constants: V=128, E=256, H=4, B=1024, L=64
// Algebra: attn out folds V away: out = sv @ Wv^T, Wv folded into fc (W').
//          QK^T = Y @ x2^T with Y = X2 @ (Wq^T Wk) (NT precomputed, per head).
// 5 launches (R10 proven config): prep (x2t+NT+wfold+posmean) -> gemm128 (Y)
//   -> attn (sv + xmean) -> fc (K-split x4, 256 blocks) -> final (1024 blocks).

typedef __attribute__((ext_vector_type(8))) short bf16x8;
typedef __attribute__((ext_vector_type(4))) float f32x4;

__device__ __forceinline__ float wred_sum(float v) {
#pragma unroll
  for (int off = 32; off > 0; off >>= 1) v += __shfl_xor(v, off, 64);
  return v;
}
__device__ __forceinline__ float bf2f(unsigned short u) {
  union { unsigned int i; float f; } x; x.i = ((unsigned int)u) << 16; return x.f;
}
__device__ __forceinline__ unsigned short f2bf(float f) {
  union { float f; unsigned int i; } x; x.f = f;
  unsigned int r = x.i + 0x7FFFu + ((x.i >> 16) & 1u);
  return (unsigned short)(r >> 16);
}
__device__ __forceinline__ void gld16(const unsigned short* g, unsigned short* l) {
  __builtin_amdgcn_global_load_lds(
      (const __attribute__((address_space(1))) unsigned int*)g,
      (__attribute__((address_space(3))) unsigned int*)l, 16, 0, 0);
}
// fast freq = 10000^(-i/128) = exp2(-i * log2(1e4)/128)
__device__ __forceinline__ float fast_freq(float i) {
  return exp2f(i * (-13.287712379549449f / 128.0f));
}

// ---------------- prep super-kernel ----------------
// blocks 0..63:    NT[h] tiles:    NT[h][e2][e1] = sum_i Wk[i,e2] Wq[i,e1]
// blocks 64..127:  wfold tiles:    wfold[o][h*256+e] = sum_e' fc_w[o][h*256+e'] Wv_h[e'][e]
// block 128:       posmean
// blocks 129..2176: x2t rows (4/block)
__global__ __launch_bounds__(256) void prep_kernel(const float* qkv_w, const float* fc_w,
                                                   const float* emb, const float* ln0_g,
                                                   const float* ln0_b, float* posmean,
                                                   unsigned short* NTb, unsigned short* wfoldb,
                                                   unsigned short* x2tb) {
  __shared__ float T[64][65];
  __shared__ unsigned short As[64 * 64];
  __shared__ unsigned short Bs[64 * 64];
  int bid = blockIdx.x, t = threadIdx.x;

  if (bid < 128) {
    int w = t >> 6, lane = t & 63;
    int li = lane & 15, hi = lane >> 4;
    int r = t >> 4, c4 = (t & 15) * 4;
    bool isNT = bid < 64;
    int sub = isNT ? bid : bid - 64;
    int h = sub >> 4;
    int tm = (sub >> 2) & 3;
    int tn = sub & 3;
    int m0 = tm * 64, n0 = tn * 64;
    f32x4 acc[4] = {};
    for (int kt = 0; kt < 4; ++kt) {
      int k0 = kt * 64;
      if (isNT) {
        __syncthreads();
#pragma unroll
        for (int rep = 0; rep < 4; ++rep) {
          int il = rep * 16 + r;
          float4 v = *(const float4*)(qkv_w + (size_t)(h * 768 + 256 + k0 + il) * 256 + m0 + c4);
          T[il][c4] = v.x; T[il][c4 + 1] = v.y; T[il][c4 + 2] = v.z; T[il][c4 + 3] = v.w;
        }
        __syncthreads();
#pragma unroll
        for (int rep = 0; rep < 4; ++rep) {
          int el = rep * 16 + r;
          As[el * 64 + c4 + 0] = f2bf(T[c4 + 0][el]);
          As[el * 64 + c4 + 1] = f2bf(T[c4 + 1][el]);
          As[el * 64 + c4 + 2] = f2bf(T[c4 + 2][el]);
          As[el * 64 + c4 + 3] = f2bf(T[c4 + 3][el]);
        }
      } else {
        __syncthreads();
#pragma unroll
        for (int rep = 0; rep < 4; ++rep) {
          int rl = rep * 16 + r;
          float4 v = *(const float4*)(fc_w + (size_t)(m0 + rl) * 1024 + h * 256 + k0 + c4);
          As[rl * 64 + c4 + 0] = f2bf(v.x);
          As[rl * 64 + c4 + 1] = f2bf(v.y);
          As[rl * 64 + c4 + 2] = f2bf(v.z);
          As[rl * 64 + c4 + 3] = f2bf(v.w);
        }
      }
      {
        int sel = isNT ? 0 : 512;
        __syncthreads();
#pragma unroll
        for (int rep = 0; rep < 4; ++rep) {
          int il = rep * 16 + r;
          float4 v = *(const float4*)(qkv_w + (size_t)(h * 768 + sel + k0 + il) * 256 + n0 + c4);
          T[il][c4] = v.x; T[il][c4 + 1] = v.y; T[il][c4 + 2] = v.z; T[il][c4 + 3] = v.w;
        }
        __syncthreads();
#pragma unroll
        for (int rep = 0; rep < 4; ++rep) {
          int el = rep * 16 + r;
          Bs[el * 64 + c4 + 0] = f2bf(T[c4 + 0][el]);
          Bs[el * 64 + c4 + 1] = f2bf(T[c4 + 1][el]);
          Bs[el * 64 + c4 + 2] = f2bf(T[c4 + 2][el]);
          Bs[el * 64 + c4 + 3] = f2bf(T[c4 + 3][el]);
        }
      }
      __syncthreads();
#pragma unroll
      for (int kk = 0; kk < 2; ++kk) {
        bf16x8 bf = *(const bf16x8*)(Bs + (w * 16 + li) * 64 + kk * 32 + hi * 8);
#pragma unroll
        for (int m = 0; m < 4; ++m) {
          bf16x8 af = *(const bf16x8*)(As + (m * 16 + li) * 64 + kk * 32 + hi * 8);
          acc[m] = __builtin_amdgcn_mfma_f32_16x16x32_bf16(af, bf, acc[m], 0, 0, 0);
        }
      }
    }
    if (isNT) {
      unsigned short* C = NTb + (size_t)h * 65536;
      int col = n0 + w * 16 + li;
#pragma unroll
      for (int m = 0; m < 4; ++m)
#pragma unroll
        for (int j = 0; j < 4; ++j)
          C[(size_t)(m0 + m * 16 + hi * 4 + j) * 256 + col] = f2bf(acc[m][j]);
    } else {
      int col = h * 256 + n0 + w * 16 + li;
#pragma unroll
      for (int m = 0; m < 4; ++m)
#pragma unroll
        for (int j = 0; j < 4; ++j)
          wfoldb[(size_t)(m0 + m * 16 + hi * 4 + j) * 1024 + col] = f2bf(acc[m][j]);
    }
  } else if (bid == 128) {
    int e = t;
    float freq = fast_freq((float)(e >> 1));
    float s = 0.f;
    for (int l = 0; l < 64; ++l) {
      float ph = (float)l * freq;
      s += (e & 1) ? __cosf(ph) : __sinf(ph);
    }
    posmean[e] = s * (1.0f / 64.0f);
  } else {
    int w = t >> 6, lane = t & 63;
    int row = (bid - 129) * 4 + w;
    int c = row >> 6, l = row & 63;
    int e0 = lane * 4;
    float fr0 = fast_freq((float)(e0 >> 1));
    float fr1 = fast_freq((float)(e0 >> 1) + 1.0f);
    float p0 = (float)l * fr0, p1 = (float)l * fr1;
    float4 pv = make_float4(__sinf(p0), __cosf(p0), __sinf(p1), __cosf(p1));
    float4 ev = *(const float4*)(emb + c * 256 + e0);
    float v0 = ev.x + pv.x, v1 = ev.y + pv.y, v2 = ev.z + pv.z, v3 = ev.w + pv.w;
    float s = wred_sum(v0 + v1 + v2 + v3);
    float q = wred_sum(v0 * v0 + v1 * v1 + v2 * v2 + v3 * v3);
    float mean = s * (1.0f / 256.0f);
    float var = q * (1.0f / 256.0f) - mean * mean;
    float rstd = rsqrtf(var + 1e-5f);
    float4 gv = *(const float4*)(ln0_g + e0);
    float4 bv = *(const float4*)(ln0_b + e0);
    *(ushort4*)(x2tb + (size_t)row * 256 + e0) = make_ushort4(
        f2bf((v0 - mean) * rstd * gv.x + bv.x + pv.x),
        f2bf((v1 - mean) * rstd * gv.y + bv.y + pv.y),
        f2bf((v2 - mean) * rstd * gv.z + bv.z + pv.z),
        f2bf((v3 - mean) * rstd * gv.w + bv.w + pv.w));
  }
}

// ---------------- Y GEMM: yt[r][h*256+e2] = sum_e1 x2tb[r][e1] * NT[h][e2][e1] ----------------
__global__ __launch_bounds__(256) void gemm128_kernel(const unsigned short* A,
                                                      const unsigned short* B,
                                                      unsigned short* C) {
  __shared__ unsigned short S[2 * 128 * 64];
  unsigned short* As = S;
  unsigned short* Bs = S + 128 * 64;
  int t = threadIdx.x, w = t >> 6, lane = t & 63;
  int m0 = blockIdx.y * 128, n0 = blockIdx.x * 128, z = blockIdx.z;
  B += (size_t)z * 65536;
  int wr = w >> 1, wc = w & 1;
  f32x4 acc[4][4] = {};
  int r_in = lane >> 3, cb = (lane & 7) * 8;
  for (int kt = 0; kt < 4; ++kt) {
#pragma unroll
    for (int it = 0; it < 4; ++it) {
      int rowblk = it * 32 + w * 8;
      gld16(A + (size_t)(m0 + rowblk + r_in) * 256 + kt * 64 + cb, As + rowblk * 64);
      gld16(B + (size_t)(n0 + rowblk + r_in) * 256 + kt * 64 + cb, Bs + rowblk * 64);
    }
    __syncthreads();
#pragma unroll
    for (int kk = 0; kk < 2; ++kk) {
      bf16x8 af[4], bfr[4];
#pragma unroll
      for (int m = 0; m < 4; ++m)
        af[m] = *(const bf16x8*)(As + (wr * 64 + m * 16 + (lane & 15)) * 64 + kk * 32 + (lane >> 4) * 8);
#pragma unroll
      for (int n = 0; n < 4; ++n)
        bfr[n] = *(const bf16x8*)(Bs + (wc * 64 + n * 16 + (lane & 15)) * 64 + kk * 32 + (lane >> 4) * 8);
#pragma unroll
      for (int m = 0; m < 4; ++m)
#pragma unroll
        for (int n = 0; n < 4; ++n)
          acc[m][n] = __builtin_amdgcn_mfma_f32_16x16x32_bf16(af[m], bfr[n], acc[m][n], 0, 0, 0);
    }
    __syncthreads();
  }
  unsigned short* Cs = S;
#pragma unroll
  for (int m = 0; m < 4; ++m)
#pragma unroll
    for (int n = 0; n < 4; ++n) {
      int row = wr * 64 + m * 16 + ((lane >> 4)) * 4;
      int col = wc * 64 + n * 16 + (lane & 15);
#pragma unroll
      for (int j = 0; j < 4; ++j)
        Cs[(row + j) * 128 + col] = f2bf(acc[m][n][j]);
    }
  __syncthreads();
#pragma unroll
  for (int it = 0; it < 8; ++it) {
    int row = it * 16 + (t >> 4);
    int ce = (t & 15) * 8;
    *(bf16x8*)(C + (size_t)(m0 + row) * 1024 + z * 256 + n0 + ce) =
        *(const bf16x8*)(Cs + row * 128 + ce);
  }
}

// ---------------- attention: block = b (512 thr, 8 waves); wave = (head, q-half) ----------------
// No-max softmax (exp args bounded); emits sv + xmean.
__global__ __launch_bounds__(512, 4) void attn_kernel(const int* cc, const unsigned short* yt,
                                                      const unsigned short* x2tb,
                                                      const float* posmean,
                                                      unsigned short* svb, float* xmb) {
  __shared__ unsigned short X2s[4 * 4112];
  __shared__ float s_sp[8][64];
  __shared__ float s_nm[64];
  __shared__ int s_cc[64];
  __shared__ float s_nwinv;
  int b = blockIdx.x;
  int t = threadIdx.x, w = t >> 6, lane = t & 63;
  int li = lane & 15, hi = lane >> 4;
  int h = w >> 1, mh = w & 1;

  if (t < 64) {
    int c = cc[b * 64 + t];
    s_cc[t] = c;
    s_nm[t] = (c != 0) ? 1.0f : 0.0f;
  }
  __syncthreads();
  if (t < 64) {
    float s = wred_sum(s_nm[t]);
    if (t == 0) s_nwinv = 1.0f / s;
  }

  int sr = lane >> 3;
  int sg = (lane & 7) ^ sr;
  {
    int idx = w * 8 + sr;
    size_t rbase = (size_t)(s_cc[idx] * 64 + idx) * 256;
#pragma unroll
    for (int ecc = 0; ecc < 4; ++ecc)
      gld16(x2tb + rbase + ecc * 64 + sg * 8, X2s + ecc * 4112 + w * 512);
  }

  const unsigned short* rowp[2];
#pragma unroll
  for (int m = 0; m < 2; ++m) {
    int idx = mh * 32 + m * 16 + li;
    rowp[m] = yt + (size_t)(s_cc[idx] * 64 + idx) * 1024 + h * 256;
  }
  float nmv[4];
#pragma unroll
  for (int n = 0; n < 4; ++n) nmv[n] = s_nm[n * 16 + li];

  bf16x8 ybuf[4][4];
#pragma unroll
  for (int ec = 0; ec < 2; ++ec)
#pragma unroll
    for (int kk = 0; kk < 2; ++kk)
#pragma unroll
      for (int m = 0; m < 2; ++m)
        ybuf[ec][kk * 2 + m] = *(const bf16x8*)(rowp[m] + ec * 64 + kk * 32 + hi * 8);

  __syncthreads();

  f32x4 acc[2][4] = {};
#pragma unroll
  for (int ec = 0; ec < 4; ++ec) {
    if (ec < 2) {
#pragma unroll
      for (int kk = 0; kk < 2; ++kk)
#pragma unroll
        for (int m = 0; m < 2; ++m)
          ybuf[ec + 2][kk * 2 + m] = *(const bf16x8*)(rowp[m] + (ec + 2) * 64 + kk * 32 + hi * 8);
    }
    __builtin_amdgcn_sched_barrier(0);
    __builtin_amdgcn_s_setprio(1);
#pragma unroll
    for (int kk = 0; kk < 2; ++kk)
#pragma unroll
      for (int n = 0; n < 4; ++n) {
        int rk = n * 16 + li;
        bf16x8 bf = *(const bf16x8*)(X2s + ec * 4112 + rk * 64 + (((kk * 4 + hi) ^ (rk & 7)) * 8));
#pragma unroll
        for (int m = 0; m < 2; ++m)
          acc[m][n] = __builtin_amdgcn_mfma_f32_16x16x32_bf16(ybuf[ec][kk * 2 + m], bf, acc[m][n], 0, 0, 0);
      }
    __builtin_amdgcn_s_setprio(0);
  }

  float sc[4] = {0.f, 0.f, 0.f, 0.f};
#pragma unroll
  for (int m = 0; m < 2; ++m)
#pragma unroll
    for (int j = 0; j < 4; ++j) {
      float nmq = s_nm[mh * 32 + m * 16 + hi * 4 + j];
      float p[4];
#pragma unroll
      for (int n = 0; n < 4; ++n) p[n] = nmv[n] * __expf(acc[m][n][j] * 0.0625f);
      float s = (p[0] + p[1]) + (p[2] + p[3]);
      s += __shfl_xor(s, 1, 64);
      s += __shfl_xor(s, 2, 64);
      s += __shfl_xor(s, 4, 64);
      s += __shfl_xor(s, 8, 64);
      float f = nmq / s;
#pragma unroll
      for (int n = 0; n < 4; ++n) sc[n] += p[n] * f;
    }
#pragma unroll
  for (int n = 0; n < 4; ++n) {
    sc[n] += __shfl_xor(sc[n], 16, 64);
    sc[n] += __shfl_xor(sc[n], 32, 64);
  }
  if (hi == 0) {
#pragma unroll
    for (int n = 0; n < 4; ++n) s_sp[w][n * 16 + li] = sc[n];
  }
  __syncthreads();

  {
    float nwinv = s_nwinv;
    int c0 = mh * 128 + lane * 2;
    int chunk = c0 >> 6;
    int cin = c0 & 63;
    int cg = cin >> 3, ce = cin & 7;
    const unsigned short* Xc = X2s + chunk * 4112;
    const float* spa = s_sp[h * 2];
    const float* spb = s_sp[h * 2 + 1];
    float o0 = 0.f, o1 = 0.f;
#pragma unroll
    for (int k = 0; k < 64; ++k) {
      float sk = (spa[k] + spb[k]) * nwinv;
      const unsigned short* p = Xc + k * 64 + ((cg ^ (k & 7)) * 8) + ce;
      o0 = fmaf(sk, bf2f(p[0]), o0);
      o1 = fmaf(sk, bf2f(p[1]), o1);
    }
    ushort2 ov; ov.x = f2bf(o0); ov.y = f2bf(o1);
    *(ushort2*)(svb + (size_t)b * 1024 + h * 256 + c0) = ov;
  }

  {
    int cidx = w * 32 + (lane & 31);
    int chunk = cidx >> 6, cin = cidx & 63;
    int cg = cin >> 3, ce = cin & 7;
    const unsigned short* Xc = X2s + chunk * 4112;
    int r0 = lane >> 5;
    float s = 0.f;
#pragma unroll
    for (int kk = 0; kk < 32; ++kk) {
      int k = r0 + kk * 2;
      s += bf2f(Xc[k * 64 + ((cg ^ (k & 7)) * 8) + ce]);
    }
    s += __shfl_xor(s, 32, 64);
    if (lane < 32)
      xmb[(size_t)b * 256 + cidx] = s * (1.0f / 64.0f) - posmean[cidx];
  }
}

// ---------------- fc GEMM (K-split x4): fco_part[z] = svb @ wfold^T over K-quarter z ----------------
__global__ __launch_bounds__(256) void fc_mfma_kernel(const unsigned short* aob,
                                                      const unsigned short* fc_wb,
                                                      float* fco) {
  __shared__ unsigned short As[64 * 64];
  __shared__ unsigned short Bs[64 * 64];
  int t = threadIdx.x, w = t >> 6, lane = t & 63;
  int li = lane & 15, hi = lane >> 4;
  int n0 = blockIdx.x * 64;
  int m0 = blockIdx.y * 64;
  int z = blockIdx.z;
  int r_in = lane >> 3, cb = (lane & 7) * 8;
  f32x4 acc[4] = {};
  for (int kt = z * 4; kt < z * 4 + 4; ++kt) {
#pragma unroll
    for (int it = 0; it < 2; ++it) {
      int rowblk = it * 32 + w * 8;
      gld16(aob + (size_t)(m0 + rowblk + r_in) * 1024 + kt * 64 + cb, As + rowblk * 64);
      gld16(fc_wb + (size_t)(n0 + rowblk + r_in) * 1024 + kt * 64 + cb, Bs + rowblk * 64);
    }
    __syncthreads();
#pragma unroll
    for (int kk = 0; kk < 2; ++kk) {
      bf16x8 bf = *(const bf16x8*)(Bs + (w * 16 + li) * 64 + kk * 32 + hi * 8);
#pragma unroll
      for (int m = 0; m < 4; ++m) {
        bf16x8 af = *(const bf16x8*)(As + (m * 16 + li) * 64 + kk * 32 + hi * 8);
        acc[m] = __builtin_amdgcn_mfma_f32_16x16x32_bf16(af, bf, acc[m], 0, 0, 0);
      }
    }
    __syncthreads();
  }
  int col = n0 + w * 16 + li;
  float* out = fco + (size_t)z * 262144;
#pragma unroll
  for (int m = 0; m < 4; ++m)
#pragma unroll
    for (int j = 0; j < 4; ++j)
      out[(size_t)(m0 + m * 16 + hi * 4 + j) * 256 + col] = acc[m][j];
}

// ---------------- final: sum fc partials + bias + xm + LN chain ----------------
__device__ __forceinline__ float block_ln(float v, int t, float eps, const float* g,
                                          const float* b, float* s_part) {
  int w = t >> 6, lane = t & 63;
  __syncthreads();
  float s = wred_sum(v), q = wred_sum(v * v);
  if (lane == 0) { s_part[w] = s; s_part[4 + w] = q; }
  __syncthreads();
  float sum = s_part[0] + s_part[1] + s_part[2] + s_part[3];
  float sq = s_part[4] + s_part[5] + s_part[6] + s_part[7];
  float mean = sum * (1.0f / 256.0f);
  float var = sq * (1.0f / 256.0f) - mean * mean;
  float rstd = rsqrtf(var + eps);
  return (v - mean) * rstd * g[t] + b[t];
}

__global__ __launch_bounds__(256) void final_kernel(
    const float* xmb, const float* fco, const float* fc_b,
    const float* sln_g, const float* sln_b, const float* ln1_g, const float* ln1_b,
    const float* ffln_g, const float* ffln_b, const float* ln2_g, const float* ln2_b,
    float* out) {
  __shared__ float s_part[8];
  int b = blockIdx.x, t = threadIdx.x;
  size_t o = (size_t)b * 256 + t;
  float xm = xmb[o];
  float v = fco[o] + fco[262144 + o] + fco[2 * 262144 + o] + fco[3 * 262144 + o] + fc_b[t];
  v = block_ln(v, t, 1e-5f, sln_g, sln_b, s_part);
  v = v + xm;
  v = block_ln(v, t, 1e-5f, ln1_g, ln1_b, s_part);
  float ff = block_ln(v, t, 1e-6f, ffln_g, ffln_b, s_part);
  float w2 = ff + v;
  float fin = block_ln(w2, t, 1e-5f, ln2_g, ln2_b, s_part);
  out[b * 256 + t] = fin;
}

extern "C" void kernel_launch(void* const* d_in, const int* in_sizes, int n_in,
                              void* d_out, int out_size, void* d_ws, size_t ws_size,
                              hipStream_t stream) {
  const int* char_code = (const int*)d_in[0];
  const float* emb    = (const float*)d_in[2];
  const float* qkv_w  = (const float*)d_in[3];
  const float* ln0_g  = (const float*)d_in[4];
  const float* ln0_b  = (const float*)d_in[5];
  const float* fc_w   = (const float*)d_in[6];
  const float* fc_b   = (const float*)d_in[7];
  const float* sln_g  = (const float*)d_in[8];
  const float* sln_b  = (const float*)d_in[9];
  const float* ln1_g  = (const float*)d_in[10];
  const float* ln1_b  = (const float*)d_in[11];
  const float* ffln_g = (const float*)d_in[16];
  const float* ffln_b = (const float*)d_in[17];
  const float* ln2_g  = (const float*)d_in[18];
  const float* ln2_b  = (const float*)d_in[19];

  float* ws = (float*)d_ws;
  float* posmean = ws;                                      // 256 f32
  unsigned short* x2tb  = (unsigned short*)(posmean + 256); // 8192*256
  unsigned short* yt    = x2tb + (size_t)8192 * 256;        // 8192*1024
  unsigned short* NTb   = yt + (size_t)8192 * 1024;         // 4*256*256
  unsigned short* wfoldb= NTb + 262144;                     // 256*1024
  unsigned short* svb   = wfoldb + 262144;                  // 1024*1024
  float* fco = (float*)(svb + (size_t)1024 * 1024);         // 4 * 1024*256 f32
  float* xmb = fco + (size_t)4 * 262144;                    // 1024*256 f32

  prep_kernel<<<2177, 256, 0, stream>>>(qkv_w, fc_w, emb, ln0_g, ln0_b, posmean,
                                        NTb, wfoldb, x2tb);
  gemm128_kernel<<<dim3(2, 64, 4), 256, 0, stream>>>(x2tb, NTb, yt);
  attn_kernel<<<1024, 512, 0, stream>>>(char_code, yt, x2tb, posmean, svb, xmb);
  fc_mfma_kernel<<<dim3(4, 16, 4), 256, 0, stream>>>(svb, wfoldb, fco);
  final_kernel<<<1024, 256, 0, stream>>>(xmb, fco, fc_b,
                                         sln_g, sln_b, ln1_g, ln1_b,
                                         ffln_g, ffln_b, ln2_g, ln2_b, (float*)d_out);
}